// Round 10
// baseline (290.358 us; speedup 1.0000x reference)
//
#include <hip/hip_runtime.h>

#define N_NODES 100000
#define N_EDGES 1600000
#define DD 64
#define NLAYER 3
#define NUM_GRAPHS 50
#define NODES_PER_GRAPH 2000
#define CAT_D (NLAYER * DD)
#define MROWS 80          // rows per layer block; 25 blocks/graph, no straddle
#define MLP_THREADS 320   // 5 waves x 16-row strips
#define LPITCH 72         // LDS row pitch in ushorts

// binned CSR build
#define NPB 256                         // nodes per bucket (dst >> 8)
#define NB ((N_NODES + NPB - 1) / NPB)  // 391 buckets
#define BPAD 6144                       // padded region per bucket
#define ECHUNK 4096                     // edges per bin_kernel block

// gather
#define WECAP 288                       // LDS edge slots per wave-round (8 nodes, mean 128, +14 sigma)

typedef __attribute__((ext_vector_type(8))) short short8;
typedef __attribute__((ext_vector_type(4))) float float4v;

__device__ __forceinline__ unsigned short f2bf(float f) {
    unsigned u = __float_as_uint(f);
    unsigned r = u + 0x7FFF + ((u >> 16) & 1);   // RTNE
    return (unsigned short)(r >> 16);
}
__device__ __forceinline__ float bflo(unsigned u) {
    return __uint_as_float(u << 16);
}
__device__ __forceinline__ float bfhi(unsigned u) {
    return __uint_as_float(u & 0xFFFF0000u);
}

// ---------------------------------------------------------------------------
// Prep: x (fp32) -> bf16
// ---------------------------------------------------------------------------
__global__ __launch_bounds__(256) void convert_x_kernel(
    const float* __restrict__ x, unsigned short* __restrict__ hx)
{
    int i = (blockIdx.x * blockDim.x + threadIdx.x) * 4;
    if (i + 3 < N_NODES * DD) {
        float4 v = *(const float4*)&x[i];
        hx[i]     = f2bf(v.x);
        hx[i + 1] = f2bf(v.y);
        hx[i + 2] = f2bf(v.z);
        hx[i + 3] = f2bf(v.w);
    }
}

// ---------------------------------------------------------------------------
// Prep: W1,W2 (L,K,N fp32) -> transposed bf16 [l][n][k]; also init cursors
// ---------------------------------------------------------------------------
__global__ __launch_bounds__(256) void convert_w_kernel(
    const float* __restrict__ W1, const float* __restrict__ W2,
    unsigned short* __restrict__ W1t, unsigned short* __restrict__ W2t,
    int* __restrict__ cursor)
{
    int idx = blockIdx.x * blockDim.x + threadIdx.x;
    if (idx < NB) cursor[idx] = idx * BPAD;
    if (idx >= 2 * NLAYER * DD * DD) return;
    int which = idx / (NLAYER * DD * DD);
    int rem = idx % (NLAYER * DD * DD);
    int l = rem / (DD * DD);
    int t = rem % (DD * DD);
    int n = t >> 6, k = t & 63;
    const float* W = which ? W2 : W1;
    unsigned short* Wt = which ? W2t : W1t;
    Wt[l * DD * DD + n * DD + k] = f2bf(W[l * DD * DD + k * DD + n]);
}

// ---------------------------------------------------------------------------
// Pass A: bin edges by dst-bucket (LDS-staged grouped writes).
// ---------------------------------------------------------------------------
__global__ __launch_bounds__(256) void bin_kernel(
    const int* __restrict__ src, const int* __restrict__ dst,
    const float* __restrict__ ew, int* __restrict__ cursor,
    uint2* __restrict__ binned)
{
    __shared__ uint2 stage[ECHUNK];
    __shared__ unsigned short bkt[ECHUNK];
    __shared__ int cnt[512];
    __shared__ int base[512];
    __shared__ int ssum[256];
    __shared__ int gbase[512];

    const int tid = threadIdx.x;
    const int start = blockIdx.x * ECHUNK;
    const int count = min(ECHUNK, N_EDGES - start);

    cnt[tid] = 0;
    cnt[tid + 256] = 0;
    __syncthreads();

    unsigned pk1[16], pk2[16];
    int eb[16], er[16];
    #pragma unroll
    for (int k = 0; k < 16; ++k) {
        int i = tid + k * 256;
        if (i < count) {
            int e = start + i;
            int s = src[e];
            int d = dst[e];
            float w = ew[e];
            int b = d >> 8;
            pk1[k] = (unsigned)s | ((unsigned)(d & 255) << 17);
            pk2[k] = __float_as_uint(w);
            eb[k] = b;
            er[k] = atomicAdd(&cnt[b], 1);
        } else {
            eb[k] = -1;
        }
    }
    __syncthreads();

    int c0 = cnt[2 * tid], c1 = cnt[2 * tid + 1];
    ssum[tid] = c0 + c1;
    __syncthreads();
    for (int off = 1; off < 256; off <<= 1) {
        int x = (tid >= off) ? ssum[tid - off] : 0;
        __syncthreads();
        ssum[tid] += x;
        __syncthreads();
    }
    int ex = (tid > 0) ? ssum[tid - 1] : 0;
    base[2 * tid] = ex;
    base[2 * tid + 1] = ex + c0;

    if (2 * tid < NB && c0 > 0)     gbase[2 * tid]     = atomicAdd(&cursor[2 * tid], c0);
    if (2 * tid + 1 < NB && c1 > 0) gbase[2 * tid + 1] = atomicAdd(&cursor[2 * tid + 1], c1);
    __syncthreads();

    #pragma unroll
    for (int k = 0; k < 16; ++k) {
        if (eb[k] >= 0) {
            int p = base[eb[k]] + er[k];
            stage[p].x = pk1[k];
            stage[p].y = pk2[k];
            bkt[p] = (unsigned short)eb[k];
        }
    }
    __syncthreads();

    for (int i = tid; i < count; i += 256) {
        int b = bkt[i];
        binned[gbase[b] + (i - base[b])] = stage[i];
    }
}

// ---------------------------------------------------------------------------
// Pass B: per-bucket local sort by exact dst; emits beg[]/end[].
// ---------------------------------------------------------------------------
__global__ __launch_bounds__(256) void localsort_kernel(
    const int* __restrict__ cursor, const uint2* __restrict__ binned,
    uint2* __restrict__ s_edge, int* __restrict__ beg, int* __restrict__ end)
{
    __shared__ int deg[NPB];
    __shared__ int rb[NPB];
    __shared__ int cur[NPB];

    const int nb = blockIdx.x;
    const int tid = threadIdx.x;
    const int bstart = nb * BPAD;
    const int count = cursor[nb] - bstart;

    deg[tid] = 0;
    __syncthreads();
    for (int i = tid; i < count; i += 256) {
        unsigned w = binned[bstart + i].x;
        atomicAdd(&deg[(w >> 17) & 255], 1);
    }
    __syncthreads();

    int v = deg[tid];
    rb[tid] = v;
    __syncthreads();
    for (int off = 1; off < 256; off <<= 1) {
        int x = (tid >= off) ? rb[tid - off] : 0;
        __syncthreads();
        rb[tid] += x;
        __syncthreads();
    }
    int ex = rb[tid] - v;
    cur[tid] = ex;
    int node = nb * NPB + tid;
    if (node < N_NODES) {
        beg[node] = bstart + ex;
        end[node] = bstart + ex + v;
    }
    __syncthreads();

    for (int i = tid; i < count; i += 256) {
        uint2 e = binned[bstart + i];
        int d = (e.x >> 17) & 255;
        int r = atomicAdd(&cur[d], 1);
        uint2 o;
        o.x = e.x & 0x1FFFF;
        o.y = e.y;
        s_edge[bstart + r] = o;
    }
}

// ---------------------------------------------------------------------------
// Fused per-layer kernel: gather (v5 eighth-wave) + MFMA MLP + pooling.
// Block = 5 waves x 16-row strip = 80 nodes. Each wave gathers its strip in
// 2 rounds of 8 nodes (8-lane group per node, uint4 = feature octet),
// writing z as bf16 DIRECTLY into its wave-private zs strip (no global
// z round-trip). Then the in-place MFMA MLP runs on zs:
//   t = leaky(z@W1+b1); z2 = t@W2+b2; h_out = leaky(z2) (skipped on last
//   layer); pooled[g] += colsum(z2).
// ---------------------------------------------------------------------------
__global__ __launch_bounds__(MLP_THREADS) void layer_kernel(
    const uint4* __restrict__ h4, const int* __restrict__ beg,
    const int* __restrict__ end, const uint2* __restrict__ s_edge,
    const float* __restrict__ eps, int l,
    const unsigned short* __restrict__ W1t, const unsigned short* __restrict__ W2t,
    const float* __restrict__ b1l, const float* __restrict__ b2l,
    unsigned short* __restrict__ h_out, float* __restrict__ pooled)
{
    __shared__ __align__(16) unsigned short zs[MROWS * LPITCH];
    __shared__ __align__(16) unsigned short w1s[DD * LPITCH];
    __shared__ __align__(16) unsigned short w2s[DD * LPITCH];
    __shared__ uint2 eds[5 * WECAP];
    __shared__ float red[5 * DD];

    const int tid  = threadIdx.x;
    const int lane = tid & 63;
    const int w    = tid >> 6;
    const long base = (long)blockIdx.x * MROWS;

    // ---- stage weights (consumed after the barrier below) ----
    for (int idx = tid; idx < DD * 8; idx += MLP_THREADS) {
        int row = idx >> 3, seg = idx & 7;
        *(int4*)&w1s[row * LPITCH + seg * 8] =
            *(const int4*)&W1t[(size_t)l * DD * DD + row * DD + seg * 8];
        *(int4*)&w2s[row * LPITCH + seg * 8] =
            *(const int4*)&W2t[(size_t)l * DD * DD + row * DD + seg * 8];
    }

    // ---- gather phase: 2 rounds x 8 nodes -> wave's 16-row zs strip ----
    const int o  = lane >> 3;        // node slot in round (0..7)
    const int fl = lane & 7;         // feature octet
    const float e1 = 1.0f + eps[l];
    const uint4* hfl = h4 + fl;
    uint2* wl = &eds[w * WECAP];

    for (int r = 0; r < 2; ++r) {
        const int nbase = (int)base + w * 16 + r * 8;
        const int node  = nbase + o;
        const int ebeg = beg[nbase];
        const int cnt  = end[nbase + 7] - ebeg;
        const bool lds_ok = (cnt <= WECAP);
        if (lds_ok) {
            for (int i = lane; i < cnt; i += 64) wl[i] = s_edge[ebeg + i];
        }
        const int gbeg = beg[node];
        const int deg  = end[node] - gbeg;

        float acc[4][8];
        #pragma unroll
        for (int c = 0; c < 4; ++c)
            #pragma unroll
            for (int j = 0; j < 8; ++j) acc[c][j] = 0.f;

        if (lds_ok) {
            const int bi = gbeg - ebeg;
            for (int it = 0; it < deg; it += 4) {
                #pragma unroll
                for (int c = 0; c < 4; ++c) {
                    bool ok = (it + c) < deg;
                    int idx = ok ? (bi + it + c) : bi;
                    uint2 p = wl[idx];
                    float wv = ok ? __uint_as_float(p.y) : 0.f;
                    uint4 rr = hfl[(long)p.x * 8];
                    acc[c][0] += bflo(rr.x) * wv;  acc[c][1] += bfhi(rr.x) * wv;
                    acc[c][2] += bflo(rr.y) * wv;  acc[c][3] += bfhi(rr.y) * wv;
                    acc[c][4] += bflo(rr.z) * wv;  acc[c][5] += bfhi(rr.z) * wv;
                    acc[c][6] += bflo(rr.w) * wv;  acc[c][7] += bfhi(rr.w) * wv;
                }
            }
        } else {
            for (int it = 0; it < deg; it += 4) {
                #pragma unroll
                for (int c = 0; c < 4; ++c) {
                    bool ok = (it + c) < deg;
                    int idx = ok ? (gbeg + it + c) : gbeg;
                    uint2 p = s_edge[idx];
                    float wv = ok ? __uint_as_float(p.y) : 0.f;
                    uint4 rr = hfl[(long)p.x * 8];
                    acc[c][0] += bflo(rr.x) * wv;  acc[c][1] += bfhi(rr.x) * wv;
                    acc[c][2] += bflo(rr.y) * wv;  acc[c][3] += bfhi(rr.y) * wv;
                    acc[c][4] += bflo(rr.z) * wv;  acc[c][5] += bfhi(rr.z) * wv;
                    acc[c][6] += bflo(rr.w) * wv;  acc[c][7] += bfhi(rr.w) * wv;
                }
            }
        }

        float s[8];
        #pragma unroll
        for (int j = 0; j < 8; ++j)
            s[j] = (acc[0][j] + acc[1][j]) + (acc[2][j] + acc[3][j]);

        uint4 selfr = hfl[(long)node * 8];
        float z0 = e1 * bflo(selfr.x) + s[0];
        float z1 = e1 * bfhi(selfr.x) + s[1];
        float z2v = e1 * bflo(selfr.y) + s[2];
        float z3 = e1 * bfhi(selfr.y) + s[3];
        float z4v = e1 * bflo(selfr.z) + s[4];
        float z5 = e1 * bfhi(selfr.z) + s[5];
        float z6 = e1 * bflo(selfr.w) + s[6];
        float z7 = e1 * bfhi(selfr.w) + s[7];
        uint4 ov;
        ov.x = (unsigned)f2bf(z0) | ((unsigned)f2bf(z1) << 16);
        ov.y = (unsigned)f2bf(z2v) | ((unsigned)f2bf(z3) << 16);
        ov.z = (unsigned)f2bf(z4v) | ((unsigned)f2bf(z5) << 16);
        ov.w = (unsigned)f2bf(z6) | ((unsigned)f2bf(z7) << 16);
        // write into wave-private strip (16B aligned: row*144 + fl*16)
        *(uint4*)&zs[(w * 16 + r * 8 + o) * LPITCH + fl * 8] = ov;
    }
    __syncthreads();   // weights visible to all; zs strips are wave-private

    // ---- MFMA phase ----
    const int m15  = lane & 15;
    const int quad = lane >> 4;

    // GEMM 1: t = leaky(z @ W1 + b1), in place into the wave's strip
    {
        short8 a0 = *(const short8*)&zs[(w * 16 + m15) * LPITCH + quad * 8];
        short8 a1 = *(const short8*)&zs[(w * 16 + m15) * LPITCH + 32 + quad * 8];
        #pragma unroll
        for (int n = 0; n < 4; ++n) {
            short8 b0 = *(const short8*)&w1s[(n * 16 + m15) * LPITCH + quad * 8];
            short8 b1 = *(const short8*)&w1s[(n * 16 + m15) * LPITCH + 32 + quad * 8];
            float4v acc = {0.f, 0.f, 0.f, 0.f};
            acc = __builtin_amdgcn_mfma_f32_16x16x32_bf16(a0, b0, acc, 0, 0, 0);
            acc = __builtin_amdgcn_mfma_f32_16x16x32_bf16(a1, b1, acc, 0, 0, 0);
            int col = n * 16 + m15;
            float bv = b1l[col];
            #pragma unroll
            for (int r = 0; r < 4; ++r) {
                int row = w * 16 + quad * 4 + r;
                float t = acc[r] + bv;
                t = t > 0.0f ? t : 0.01f * t;
                zs[row * LPITCH + col] = f2bf(t);
            }
        }
    }

    // GEMM 2: z2 = t @ W2 + b2; h = leaky(z2) in place; pool z2
    float psum[4];
    {
        short8 a0 = *(const short8*)&zs[(w * 16 + m15) * LPITCH + quad * 8];
        short8 a1 = *(const short8*)&zs[(w * 16 + m15) * LPITCH + 32 + quad * 8];
        #pragma unroll
        for (int n = 0; n < 4; ++n) {
            short8 b0 = *(const short8*)&w2s[(n * 16 + m15) * LPITCH + quad * 8];
            short8 b1 = *(const short8*)&w2s[(n * 16 + m15) * LPITCH + 32 + quad * 8];
            float4v acc = {0.f, 0.f, 0.f, 0.f};
            acc = __builtin_amdgcn_mfma_f32_16x16x32_bf16(a0, b0, acc, 0, 0, 0);
            acc = __builtin_amdgcn_mfma_f32_16x16x32_bf16(a1, b1, acc, 0, 0, 0);
            int col = n * 16 + m15;
            float bv = b2l[col];
            float ps = 0.0f;
            #pragma unroll
            for (int r = 0; r < 4; ++r) {
                int row = w * 16 + quad * 4 + r;
                float z2 = acc[r] + bv;
                ps += z2;
                float hv = z2 > 0.0f ? z2 : 0.01f * z2;
                zs[row * LPITCH + col] = f2bf(hv);
            }
            psum[n] = ps;
        }
    }
    #pragma unroll
    for (int n = 0; n < 4; ++n) {
        float v = psum[n];
        v += __shfl_xor(v, 16);
        v += __shfl_xor(v, 32);
        if (quad == 0) red[w * DD + n * 16 + m15] = v;
    }
    __syncthreads();

    if (h_out) {
        for (int idx = tid; idx < MROWS * 8; idx += MLP_THREADS) {
            int row = idx >> 3, seg = idx & 7;
            *(int4*)&h_out[(base + row) * DD + seg * 8] =
                *(const int4*)&zs[row * LPITCH + seg * 8];
        }
    }
    if (tid < DD) {
        float tot = red[tid] + red[DD + tid] + red[2 * DD + tid]
                  + red[3 * DD + tid] + red[4 * DD + tid];
        int g = blockIdx.x / (NODES_PER_GRAPH / MROWS);
        atomicAdd(&pooled[g * CAT_D + l * DD + tid], tot);
    }
}

// ---------------------------------------------------------------------------
// out[g, j] = pooled[g, :] @ lin_w[:, j] + lin_b[j]
// ---------------------------------------------------------------------------
__global__ __launch_bounds__(64) void final_kernel(
    const float* __restrict__ pooled, const float* __restrict__ lin_w,
    const float* __restrict__ lin_b, float* __restrict__ out)
{
    int g = blockIdx.x;
    int j = threadIdx.x;
    float acc = lin_b[j];
    for (int k = 0; k < CAT_D; ++k)
        acc += pooled[g * CAT_D + k] * lin_w[k * DD + j];
    out[g * DD + j] = acc;
}

extern "C" void kernel_launch(void* const* d_in, const int* in_sizes, int n_in,
                              void* d_out, int out_size, void* d_ws, size_t ws_size,
                              hipStream_t stream)
{
    const float* x     = (const float*)d_in[0];
    const int*   ei    = (const int*)d_in[1];
    const float* ew    = (const float*)d_in[2];
    const float* W1    = (const float*)d_in[4];
    const float* b1    = (const float*)d_in[5];
    const float* W2    = (const float*)d_in[6];
    const float* b2    = (const float*)d_in[7];
    const float* eps   = (const float*)d_in[8];
    const float* lin_w = (const float*)d_in[9];
    const float* lin_b = (const float*)d_in[10];
    float* out = (float*)d_out;

    const int* src = ei;
    const int* dst = ei + N_EDGES;

    char* wsb = (char*)d_ws;
    size_t off = 0;
    auto alloc = [&](size_t bytes) -> void* {
        off = (off + 15) & ~(size_t)15;
        void* p = wsb + off;
        off += bytes;
        return p;
    };
    unsigned short* hX   = (unsigned short*)alloc((size_t)N_NODES * DD * 2);
    unsigned short* hA   = (unsigned short*)alloc((size_t)N_NODES * DD * 2);
    unsigned short* W1t  = (unsigned short*)alloc((size_t)NLAYER * DD * DD * 2);
    unsigned short* W2t  = (unsigned short*)alloc((size_t)NLAYER * DD * DD * 2);
    float* pooled        = (float*)alloc((size_t)NUM_GRAPHS * CAT_D * 4);
    int*   cursor        = (int*)alloc((size_t)NB * 4);
    int*   beg           = (int*)alloc((size_t)N_NODES * 4);
    int*   end_          = (int*)alloc((size_t)N_NODES * 4);
    uint2* binned        = (uint2*)alloc((size_t)NB * BPAD * 8);
    uint2* s_edge        = (uint2*)alloc((size_t)NB * BPAD * 8);

    convert_x_kernel<<<(N_NODES * DD / 4 + 255) / 256, 256, 0, stream>>>(x, hX);
    convert_w_kernel<<<(2 * NLAYER * DD * DD + 255) / 256, 256, 0, stream>>>(
        W1, W2, W1t, W2t, cursor);

    bin_kernel<<<(N_EDGES + ECHUNK - 1) / ECHUNK, 256, 0, stream>>>(
        src, dst, ew, cursor, binned);
    localsort_kernel<<<NB, 256, 0, stream>>>(cursor, binned, s_edge, beg, end_);

    hipMemsetAsync(pooled, 0, NUM_GRAPHS * CAT_D * sizeof(float), stream);

    // layers: hX -> hA -> hX -> (none)
    const unsigned short* h_ins[3]  = { hX, hA, hX };
    unsigned short*       h_outs[3] = { hA, hX, nullptr };
    for (int l = 0; l < NLAYER; ++l) {
        layer_kernel<<<N_NODES / MROWS, MLP_THREADS, 0, stream>>>(
            (const uint4*)h_ins[l], beg, end_, s_edge, eps, l,
            W1t, W2t, b1 + (size_t)l * DD, b2 + (size_t)l * DD,
            h_outs[l], pooled);
    }

    final_kernel<<<NUM_GRAPHS, 64, 0, stream>>>(pooled, lin_w, lin_b, out);
}

// Round 11
// 277.313 us; speedup vs baseline: 1.0470x; 1.0470x over previous
//
#include <hip/hip_runtime.h>

#define N_NODES 100000
#define N_EDGES 1600000
#define DD 64
#define NLAYER 3
#define NUM_GRAPHS 50
#define NODES_PER_GRAPH 2000
#define CAT_D (NLAYER * DD)
#define MROWS 80          // rows per MLP block; 25 blocks/graph, no straddle
#define MLP_THREADS 320   // 5 waves x 16-row strips
#define LPITCH 72         // LDS row pitch in ushorts

// binned CSR build
#define NPB 256                         // nodes per bucket (dst >> 8)
#define NB ((N_NODES + NPB - 1) / NPB)  // 391 buckets
#define BPAD 6144                       // padded region per bucket
#define ECHUNK 4096                     // edges per bin_kernel block

// gather
#define GNODES 32                       // nodes per gather block (8 per wave)
#define WECAP 288                       // LDS edge slots per wave (mean 128, +14 sigma)

typedef __attribute__((ext_vector_type(8))) short short8;
typedef __attribute__((ext_vector_type(4))) float float4v;

__device__ __forceinline__ unsigned short f2bf(float f) {
    unsigned u = __float_as_uint(f);
    unsigned r = u + 0x7FFF + ((u >> 16) & 1);   // RTNE
    return (unsigned short)(r >> 16);
}
__device__ __forceinline__ float bflo(unsigned u) {
    return __uint_as_float(u << 16);
}
__device__ __forceinline__ float bfhi(unsigned u) {
    return __uint_as_float(u & 0xFFFF0000u);
}

// ---------------------------------------------------------------------------
// Prep: x (fp32) -> bf16
// ---------------------------------------------------------------------------
__global__ __launch_bounds__(256) void convert_x_kernel(
    const float* __restrict__ x, unsigned short* __restrict__ hx)
{
    int i = (blockIdx.x * blockDim.x + threadIdx.x) * 4;
    if (i + 3 < N_NODES * DD) {
        float4 v = *(const float4*)&x[i];
        hx[i]     = f2bf(v.x);
        hx[i + 1] = f2bf(v.y);
        hx[i + 2] = f2bf(v.z);
        hx[i + 3] = f2bf(v.w);
    }
}

// ---------------------------------------------------------------------------
// Prep: W1,W2 (L,K,N fp32) -> transposed bf16 [l][n][k]; also init cursors
// ---------------------------------------------------------------------------
__global__ __launch_bounds__(256) void convert_w_kernel(
    const float* __restrict__ W1, const float* __restrict__ W2,
    unsigned short* __restrict__ W1t, unsigned short* __restrict__ W2t,
    int* __restrict__ cursor)
{
    int idx = blockIdx.x * blockDim.x + threadIdx.x;
    if (idx < NB) cursor[idx] = idx * BPAD;
    if (idx >= 2 * NLAYER * DD * DD) return;
    int which = idx / (NLAYER * DD * DD);
    int rem = idx % (NLAYER * DD * DD);
    int l = rem / (DD * DD);
    int t = rem % (DD * DD);
    int n = t >> 6, k = t & 63;
    const float* W = which ? W2 : W1;
    unsigned short* Wt = which ? W2t : W1t;
    Wt[l * DD * DD + n * DD + k] = f2bf(W[l * DD * DD + k * DD + n]);
}

// ---------------------------------------------------------------------------
// Pass A: bin edges by dst-bucket (LDS-staged grouped writes).
// ---------------------------------------------------------------------------
__global__ __launch_bounds__(256) void bin_kernel(
    const int* __restrict__ src, const int* __restrict__ dst,
    const float* __restrict__ ew, int* __restrict__ cursor,
    uint2* __restrict__ binned)
{
    __shared__ uint2 stage[ECHUNK];
    __shared__ unsigned short bkt[ECHUNK];
    __shared__ int cnt[512];
    __shared__ int base[512];
    __shared__ int ssum[256];
    __shared__ int gbase[512];

    const int tid = threadIdx.x;
    const int start = blockIdx.x * ECHUNK;
    const int count = min(ECHUNK, N_EDGES - start);

    cnt[tid] = 0;
    cnt[tid + 256] = 0;
    __syncthreads();

    unsigned pk1[16], pk2[16];
    int eb[16], er[16];
    #pragma unroll
    for (int k = 0; k < 16; ++k) {
        int i = tid + k * 256;
        if (i < count) {
            int e = start + i;
            int s = src[e];
            int d = dst[e];
            float w = ew[e];
            int b = d >> 8;
            pk1[k] = (unsigned)s | ((unsigned)(d & 255) << 17);
            pk2[k] = __float_as_uint(w);
            eb[k] = b;
            er[k] = atomicAdd(&cnt[b], 1);
        } else {
            eb[k] = -1;
        }
    }
    __syncthreads();

    int c0 = cnt[2 * tid], c1 = cnt[2 * tid + 1];
    ssum[tid] = c0 + c1;
    __syncthreads();
    for (int off = 1; off < 256; off <<= 1) {
        int x = (tid >= off) ? ssum[tid - off] : 0;
        __syncthreads();
        ssum[tid] += x;
        __syncthreads();
    }
    int ex = (tid > 0) ? ssum[tid - 1] : 0;
    base[2 * tid] = ex;
    base[2 * tid + 1] = ex + c0;

    if (2 * tid < NB && c0 > 0)     gbase[2 * tid]     = atomicAdd(&cursor[2 * tid], c0);
    if (2 * tid + 1 < NB && c1 > 0) gbase[2 * tid + 1] = atomicAdd(&cursor[2 * tid + 1], c1);
    __syncthreads();

    #pragma unroll
    for (int k = 0; k < 16; ++k) {
        if (eb[k] >= 0) {
            int p = base[eb[k]] + er[k];
            stage[p].x = pk1[k];
            stage[p].y = pk2[k];
            bkt[p] = (unsigned short)eb[k];
        }
    }
    __syncthreads();

    for (int i = tid; i < count; i += 256) {
        int b = bkt[i];
        binned[gbase[b] + (i - base[b])] = stage[i];
    }
}

// ---------------------------------------------------------------------------
// Pass B: per-bucket local sort by exact dst; emits beg[]/end[].
// ---------------------------------------------------------------------------
__global__ __launch_bounds__(256) void localsort_kernel(
    const int* __restrict__ cursor, const uint2* __restrict__ binned,
    uint2* __restrict__ s_edge, int* __restrict__ beg, int* __restrict__ end)
{
    __shared__ int deg[NPB];
    __shared__ int rb[NPB];
    __shared__ int cur[NPB];

    const int nb = blockIdx.x;
    const int tid = threadIdx.x;
    const int bstart = nb * BPAD;
    const int count = cursor[nb] - bstart;

    deg[tid] = 0;
    __syncthreads();
    for (int i = tid; i < count; i += 256) {
        unsigned w = binned[bstart + i].x;
        atomicAdd(&deg[(w >> 17) & 255], 1);
    }
    __syncthreads();

    int v = deg[tid];
    rb[tid] = v;
    __syncthreads();
    for (int off = 1; off < 256; off <<= 1) {
        int x = (tid >= off) ? rb[tid - off] : 0;
        __syncthreads();
        rb[tid] += x;
        __syncthreads();
    }
    int ex = rb[tid] - v;
    cur[tid] = ex;
    int node = nb * NPB + tid;
    if (node < N_NODES) {
        beg[node] = bstart + ex;
        end[node] = bstart + ex + v;
    }
    __syncthreads();

    for (int i = tid; i < count; i += 256) {
        uint2 e = binned[bstart + i];
        int d = (e.x >> 17) & 255;
        int r = atomicAdd(&cur[d], 1);
        uint2 o;
        o.x = e.x & 0x1FFFF;
        o.y = e.y;
        s_edge[bstart + r] = o;
    }
}

// ---------------------------------------------------------------------------
// Per-layer aggregation v5: group-per-node eighth-wave.
// Wave = 8 nodes; 8-lane group owns one node (fl = lane&7 -> feature octet
// as uint4). One VMEM instruction fetches 8 different rows; 4 chains/group
// -> 32 rows in flight per wave. No cross-lane reduction. Edge runs staged
// in wave-private LDS (global fallback for runs > WECAP).
// ---------------------------------------------------------------------------
__global__ __launch_bounds__(256) void gather_kernel(
    const uint4* __restrict__ h4, const int* __restrict__ beg,
    const int* __restrict__ end, const uint2* __restrict__ s_edge,
    const float* __restrict__ eps, int l, uint4* __restrict__ z4)
{
    __shared__ uint2 eds[4 * WECAP];

    const int w    = threadIdx.x >> 6;
    const int lane = threadIdx.x & 63;
    const int o    = lane >> 3;      // node slot within wave (0..7)
    const int fl   = lane & 7;       // feature octet (features 8*fl..8*fl+7)
    const int nbase = blockIdx.x * GNODES + w * 8;
    const int node  = nbase + o;

    const int ebeg = beg[nbase];
    const int cnt  = end[nbase + 7] - ebeg;
    uint2* wl = &eds[w * WECAP];
    const bool lds_ok = (cnt <= WECAP);
    if (lds_ok) {
        for (int i = lane; i < cnt; i += 64) wl[i] = s_edge[ebeg + i];
    }

    const int gbeg = beg[node];
    const int deg  = end[node] - gbeg;

    float acc[4][8];
    #pragma unroll
    for (int c = 0; c < 4; ++c)
        #pragma unroll
        for (int j = 0; j < 8; ++j) acc[c][j] = 0.f;

    const uint4* hfl = h4 + fl;

    if (lds_ok) {
        const int bi = gbeg - ebeg;
        for (int it = 0; it < deg; it += 4) {
            #pragma unroll
            for (int c = 0; c < 4; ++c) {
                bool ok = (it + c) < deg;
                int idx = ok ? (bi + it + c) : bi;
                uint2 p = wl[idx];
                float wv = ok ? __uint_as_float(p.y) : 0.f;
                uint4 r = hfl[(long)p.x * 8];
                acc[c][0] += bflo(r.x) * wv;  acc[c][1] += bfhi(r.x) * wv;
                acc[c][2] += bflo(r.y) * wv;  acc[c][3] += bfhi(r.y) * wv;
                acc[c][4] += bflo(r.z) * wv;  acc[c][5] += bfhi(r.z) * wv;
                acc[c][6] += bflo(r.w) * wv;  acc[c][7] += bfhi(r.w) * wv;
            }
        }
    } else {
        for (int it = 0; it < deg; it += 4) {
            #pragma unroll
            for (int c = 0; c < 4; ++c) {
                bool ok = (it + c) < deg;
                int idx = ok ? (gbeg + it + c) : gbeg;
                uint2 p = s_edge[idx];
                float wv = ok ? __uint_as_float(p.y) : 0.f;
                uint4 r = hfl[(long)p.x * 8];
                acc[c][0] += bflo(r.x) * wv;  acc[c][1] += bfhi(r.x) * wv;
                acc[c][2] += bflo(r.y) * wv;  acc[c][3] += bfhi(r.y) * wv;
                acc[c][4] += bflo(r.z) * wv;  acc[c][5] += bfhi(r.z) * wv;
                acc[c][6] += bflo(r.w) * wv;  acc[c][7] += bfhi(r.w) * wv;
            }
        }
    }

    float s[8];
    #pragma unroll
    for (int j = 0; j < 8; ++j)
        s[j] = (acc[0][j] + acc[1][j]) + (acc[2][j] + acc[3][j]);

    const float e1 = 1.0f + eps[l];
    uint4 selfr = hfl[(long)node * 8];
    float z0 = e1 * bflo(selfr.x) + s[0];
    float z1 = e1 * bfhi(selfr.x) + s[1];
    float z2 = e1 * bflo(selfr.y) + s[2];
    float z3 = e1 * bfhi(selfr.y) + s[3];
    float z4v = e1 * bflo(selfr.z) + s[4];
    float z5 = e1 * bfhi(selfr.z) + s[5];
    float z6 = e1 * bflo(selfr.w) + s[6];
    float z7 = e1 * bfhi(selfr.w) + s[7];
    uint4 ov;
    ov.x = (unsigned)f2bf(z0) | ((unsigned)f2bf(z1) << 16);
    ov.y = (unsigned)f2bf(z2) | ((unsigned)f2bf(z3) << 16);
    ov.z = (unsigned)f2bf(z4v) | ((unsigned)f2bf(z5) << 16);
    ov.w = (unsigned)f2bf(z6) | ((unsigned)f2bf(z7) << 16);
    z4[(long)node * 8 + fl] = ov;
}

// ---------------------------------------------------------------------------
// MFMA MLP + pooling. 80 rows/block, 5 waves (16-row strip each).
// t and h written IN PLACE into the wave-private zs strip (no mid barrier).
// h_out == nullptr on the last layer (h would be dead) -> skip stream-out.
// ---------------------------------------------------------------------------
__global__ __launch_bounds__(MLP_THREADS) void mlp_kernel(
    const unsigned short* __restrict__ z_in,
    const unsigned short* __restrict__ W1t, const unsigned short* __restrict__ W2t,
    const float* __restrict__ b1l, const float* __restrict__ b2l,
    int l, unsigned short* __restrict__ h_out, float* __restrict__ pooled)
{
    __shared__ __align__(16) unsigned short zs[MROWS * LPITCH];
    __shared__ __align__(16) unsigned short w1s[DD * LPITCH];
    __shared__ __align__(16) unsigned short w2s[DD * LPITCH];
    __shared__ float red[5 * DD];

    const int tid  = threadIdx.x;
    const int lane = tid & 63;
    const int w    = tid >> 6;
    const int m15  = lane & 15;
    const int quad = lane >> 4;
    const long base = (long)blockIdx.x * MROWS;

    for (int idx = tid; idx < MROWS * 8; idx += MLP_THREADS) {
        int row = idx >> 3, seg = idx & 7;
        *(int4*)&zs[row * LPITCH + seg * 8] =
            *(const int4*)&z_in[(base + row) * DD + seg * 8];
    }
    for (int idx = tid; idx < DD * 8; idx += MLP_THREADS) {
        int row = idx >> 3, seg = idx & 7;
        *(int4*)&w1s[row * LPITCH + seg * 8] =
            *(const int4*)&W1t[(size_t)l * DD * DD + row * DD + seg * 8];
        *(int4*)&w2s[row * LPITCH + seg * 8] =
            *(const int4*)&W2t[(size_t)l * DD * DD + row * DD + seg * 8];
    }
    __syncthreads();

    // GEMM 1: t = leaky(z @ W1 + b1), in place into the wave's strip
    {
        short8 a0 = *(const short8*)&zs[(w * 16 + m15) * LPITCH + quad * 8];
        short8 a1 = *(const short8*)&zs[(w * 16 + m15) * LPITCH + 32 + quad * 8];
        #pragma unroll
        for (int n = 0; n < 4; ++n) {
            short8 b0 = *(const short8*)&w1s[(n * 16 + m15) * LPITCH + quad * 8];
            short8 b1 = *(const short8*)&w1s[(n * 16 + m15) * LPITCH + 32 + quad * 8];
            float4v acc = {0.f, 0.f, 0.f, 0.f};
            acc = __builtin_amdgcn_mfma_f32_16x16x32_bf16(a0, b0, acc, 0, 0, 0);
            acc = __builtin_amdgcn_mfma_f32_16x16x32_bf16(a1, b1, acc, 0, 0, 0);
            int col = n * 16 + m15;
            float bv = b1l[col];
            #pragma unroll
            for (int r = 0; r < 4; ++r) {
                int row = w * 16 + quad * 4 + r;
                float t = acc[r] + bv;
                t = t > 0.0f ? t : 0.01f * t;
                zs[row * LPITCH + col] = f2bf(t);
            }
        }
    }

    // GEMM 2: z2 = t @ W2 + b2; h = leaky(z2) in place; pool z2
    float psum[4];
    {
        short8 a0 = *(const short8*)&zs[(w * 16 + m15) * LPITCH + quad * 8];
        short8 a1 = *(const short8*)&zs[(w * 16 + m15) * LPITCH + 32 + quad * 8];
        #pragma unroll
        for (int n = 0; n < 4; ++n) {
            short8 b0 = *(const short8*)&w2s[(n * 16 + m15) * LPITCH + quad * 8];
            short8 b1 = *(const short8*)&w2s[(n * 16 + m15) * LPITCH + 32 + quad * 8];
            float4v acc = {0.f, 0.f, 0.f, 0.f};
            acc = __builtin_amdgcn_mfma_f32_16x16x32_bf16(a0, b0, acc, 0, 0, 0);
            acc = __builtin_amdgcn_mfma_f32_16x16x32_bf16(a1, b1, acc, 0, 0, 0);
            int col = n * 16 + m15;
            float bv = b2l[col];
            float ps = 0.0f;
            #pragma unroll
            for (int r = 0; r < 4; ++r) {
                int row = w * 16 + quad * 4 + r;
                float z2 = acc[r] + bv;
                ps += z2;
                float hv = z2 > 0.0f ? z2 : 0.01f * z2;
                zs[row * LPITCH + col] = f2bf(hv);
            }
            psum[n] = ps;
        }
    }
    #pragma unroll
    for (int n = 0; n < 4; ++n) {
        float v = psum[n];
        v += __shfl_xor(v, 16);
        v += __shfl_xor(v, 32);
        if (quad == 0) red[w * DD + n * 16 + m15] = v;
    }
    __syncthreads();

    if (h_out) {
        for (int idx = tid; idx < MROWS * 8; idx += MLP_THREADS) {
            int row = idx >> 3, seg = idx & 7;
            *(int4*)&h_out[(base + row) * DD + seg * 8] =
                *(const int4*)&zs[row * LPITCH + seg * 8];
        }
    }
    if (tid < DD) {
        float tot = red[tid] + red[DD + tid] + red[2 * DD + tid]
                  + red[3 * DD + tid] + red[4 * DD + tid];
        int g = blockIdx.x / (NODES_PER_GRAPH / MROWS);
        atomicAdd(&pooled[g * CAT_D + l * DD + tid], tot);
    }
}

// ---------------------------------------------------------------------------
// out[g, j] = pooled[g, :] @ lin_w[:, j] + lin_b[j]
// ---------------------------------------------------------------------------
__global__ __launch_bounds__(64) void final_kernel(
    const float* __restrict__ pooled, const float* __restrict__ lin_w,
    const float* __restrict__ lin_b, float* __restrict__ out)
{
    int g = blockIdx.x;
    int j = threadIdx.x;
    float acc = lin_b[j];
    for (int k = 0; k < CAT_D; ++k)
        acc += pooled[g * CAT_D + k] * lin_w[k * DD + j];
    out[g * DD + j] = acc;
}

extern "C" void kernel_launch(void* const* d_in, const int* in_sizes, int n_in,
                              void* d_out, int out_size, void* d_ws, size_t ws_size,
                              hipStream_t stream)
{
    const float* x     = (const float*)d_in[0];
    const int*   ei    = (const int*)d_in[1];
    const float* ew    = (const float*)d_in[2];
    const float* W1    = (const float*)d_in[4];
    const float* b1    = (const float*)d_in[5];
    const float* W2    = (const float*)d_in[6];
    const float* b2    = (const float*)d_in[7];
    const float* eps   = (const float*)d_in[8];
    const float* lin_w = (const float*)d_in[9];
    const float* lin_b = (const float*)d_in[10];
    float* out = (float*)d_out;

    const int* src = ei;
    const int* dst = ei + N_EDGES;

    char* wsb = (char*)d_ws;
    size_t off = 0;
    auto alloc = [&](size_t bytes) -> void* {
        off = (off + 15) & ~(size_t)15;
        void* p = wsb + off;
        off += bytes;
        return p;
    };
    unsigned short* hX   = (unsigned short*)alloc((size_t)N_NODES * DD * 2);
    unsigned short* hA   = (unsigned short*)alloc((size_t)N_NODES * DD * 2);
    unsigned short* zbuf = (unsigned short*)alloc((size_t)N_NODES * DD * 2);
    unsigned short* W1t  = (unsigned short*)alloc((size_t)NLAYER * DD * DD * 2);
    unsigned short* W2t  = (unsigned short*)alloc((size_t)NLAYER * DD * DD * 2);
    float* pooled        = (float*)alloc((size_t)NUM_GRAPHS * CAT_D * 4);
    int*   cursor        = (int*)alloc((size_t)NB * 4);
    int*   beg           = (int*)alloc((size_t)N_NODES * 4);
    int*   end_          = (int*)alloc((size_t)N_NODES * 4);
    uint2* binned        = (uint2*)alloc((size_t)NB * BPAD * 8);
    uint2* s_edge        = (uint2*)alloc((size_t)NB * BPAD * 8);

    convert_x_kernel<<<(N_NODES * DD / 4 + 255) / 256, 256, 0, stream>>>(x, hX);
    convert_w_kernel<<<(2 * NLAYER * DD * DD + 255) / 256, 256, 0, stream>>>(
        W1, W2, W1t, W2t, cursor);

    bin_kernel<<<(N_EDGES + ECHUNK - 1) / ECHUNK, 256, 0, stream>>>(
        src, dst, ew, cursor, binned);
    localsort_kernel<<<NB, 256, 0, stream>>>(cursor, binned, s_edge, beg, end_);

    hipMemsetAsync(pooled, 0, NUM_GRAPHS * CAT_D * sizeof(float), stream);

    // layers: hX -> hA -> hX -> (none, h dead after last layer)
    const unsigned short* h_ins[3]  = { hX, hA, hX };
    unsigned short*       h_outs[3] = { hA, hX, nullptr };
    for (int l = 0; l < NLAYER; ++l) {
        gather_kernel<<<N_NODES / GNODES, 256, 0, stream>>>(
            (const uint4*)h_ins[l], beg, end_, s_edge, eps, l,
            (uint4*)zbuf);

        mlp_kernel<<<N_NODES / MROWS, MLP_THREADS, 0, stream>>>(
            zbuf, W1t, W2t,
            b1 + (size_t)l * DD, b2 + (size_t)l * DD,
            l, h_outs[l], pooled);
    }

    final_kernel<<<NUM_GRAPHS, 64, 0, stream>>>(pooled, lin_w, lin_b, out);
}

// Round 12
// 244.772 us; speedup vs baseline: 1.1862x; 1.1329x over previous
//
#include <hip/hip_runtime.h>

#define N_NODES 100000
#define N_EDGES 1600000
#define DD 64
#define NLAYER 3
#define NUM_GRAPHS 50
#define NODES_PER_GRAPH 2000
#define CAT_D (NLAYER * DD)
#define MROWS 80          // rows per MLP block; 25 blocks/graph, no straddle
#define MLP_THREADS 320   // 5 waves x 16-row strips
#define LPITCH 72         // LDS row pitch in ushorts

// binned CSR build
#define NPB 256                         // nodes per bucket (dst >> 8)
#define NB ((N_NODES + NPB - 1) / NPB)  // 391 buckets
#define BPAD 6144                       // padded region per bucket
#define ECHUNK 4096                     // edges per bin_kernel block

// gather
#define GNODES 32                       // nodes per gather block (8 per wave)
#define WECAP 384                       // LDS edge slots per wave (mean 128, +22 sigma)

typedef __attribute__((ext_vector_type(8))) short short8;
typedef __attribute__((ext_vector_type(4))) float float4v;
typedef __attribute__((ext_vector_type(2))) float float2v;

__device__ __forceinline__ unsigned short f2bf(float f) {
    unsigned u = __float_as_uint(f);
    unsigned r = u + 0x7FFF + ((u >> 16) & 1);   // RTNE
    return (unsigned short)(r >> 16);
}
__device__ __forceinline__ float bflo(unsigned u) {
    return __uint_as_float(u << 16);
}
__device__ __forceinline__ float bfhi(unsigned u) {
    return __uint_as_float(u & 0xFFFF0000u);
}

// ---------------------------------------------------------------------------
// Prep: x (fp32) -> fp8 e4m3 (h storage format; gather converts back via HW)
// ---------------------------------------------------------------------------
__global__ __launch_bounds__(256) void convert_x_kernel(
    const float* __restrict__ x, uint2* __restrict__ hx8)
{
    int i = blockIdx.x * blockDim.x + threadIdx.x;   // one uint2 = 8 fp8
    if (i < N_NODES * DD / 8) {
        const float4* xp = (const float4*)(x + (size_t)i * 8);
        float4 a = xp[0], b = xp[1];
        int lo = 0, hi = 0;
        lo = __builtin_amdgcn_cvt_pk_fp8_f32(a.x, a.y, lo, 0);
        lo = __builtin_amdgcn_cvt_pk_fp8_f32(a.z, a.w, lo, 1);
        hi = __builtin_amdgcn_cvt_pk_fp8_f32(b.x, b.y, hi, 0);
        hi = __builtin_amdgcn_cvt_pk_fp8_f32(b.z, b.w, hi, 1);
        uint2 o; o.x = (unsigned)lo; o.y = (unsigned)hi;
        hx8[i] = o;
    }
}

// ---------------------------------------------------------------------------
// Prep: W1,W2 (L,K,N fp32) -> transposed bf16 [l][n][k]; also init cursors
// ---------------------------------------------------------------------------
__global__ __launch_bounds__(256) void convert_w_kernel(
    const float* __restrict__ W1, const float* __restrict__ W2,
    unsigned short* __restrict__ W1t, unsigned short* __restrict__ W2t,
    int* __restrict__ cursor)
{
    int idx = blockIdx.x * blockDim.x + threadIdx.x;
    if (idx < NB) cursor[idx] = idx * BPAD;
    if (idx >= 2 * NLAYER * DD * DD) return;
    int which = idx / (NLAYER * DD * DD);
    int rem = idx % (NLAYER * DD * DD);
    int l = rem / (DD * DD);
    int t = rem % (DD * DD);
    int n = t >> 6, k = t & 63;
    const float* W = which ? W2 : W1;
    unsigned short* Wt = which ? W2t : W1t;
    Wt[l * DD * DD + n * DD + k] = f2bf(W[l * DD * DD + k * DD + n]);
}

// ---------------------------------------------------------------------------
// Pass A: bin edges by dst-bucket (LDS-staged grouped writes).
// binned record: x = src(17) | d_local(8)<<17 ; y = w fp32 bits
// ---------------------------------------------------------------------------
__global__ __launch_bounds__(256) void bin_kernel(
    const int* __restrict__ src, const int* __restrict__ dst,
    const float* __restrict__ ew, int* __restrict__ cursor,
    uint2* __restrict__ binned)
{
    __shared__ uint2 stage[ECHUNK];
    __shared__ unsigned short bkt[ECHUNK];
    __shared__ int cnt[512];
    __shared__ int base[512];
    __shared__ int ssum[256];
    __shared__ int gbase[512];

    const int tid = threadIdx.x;
    const int start = blockIdx.x * ECHUNK;
    const int count = min(ECHUNK, N_EDGES - start);

    cnt[tid] = 0;
    cnt[tid + 256] = 0;
    __syncthreads();

    unsigned pk1[16], pk2[16];
    int eb[16], er[16];
    #pragma unroll
    for (int k = 0; k < 16; ++k) {
        int i = tid + k * 256;
        if (i < count) {
            int e = start + i;
            int s = src[e];
            int d = dst[e];
            float w = ew[e];
            int b = d >> 8;
            pk1[k] = (unsigned)s | ((unsigned)(d & 255) << 17);
            pk2[k] = __float_as_uint(w);
            eb[k] = b;
            er[k] = atomicAdd(&cnt[b], 1);
        } else {
            eb[k] = -1;
        }
    }
    __syncthreads();

    int c0 = cnt[2 * tid], c1 = cnt[2 * tid + 1];
    ssum[tid] = c0 + c1;
    __syncthreads();
    for (int off = 1; off < 256; off <<= 1) {
        int x = (tid >= off) ? ssum[tid - off] : 0;
        __syncthreads();
        ssum[tid] += x;
        __syncthreads();
    }
    int ex = (tid > 0) ? ssum[tid - 1] : 0;
    base[2 * tid] = ex;
    base[2 * tid + 1] = ex + c0;

    if (2 * tid < NB && c0 > 0)     gbase[2 * tid]     = atomicAdd(&cursor[2 * tid], c0);
    if (2 * tid + 1 < NB && c1 > 0) gbase[2 * tid + 1] = atomicAdd(&cursor[2 * tid + 1], c1);
    __syncthreads();

    #pragma unroll
    for (int k = 0; k < 16; ++k) {
        if (eb[k] >= 0) {
            int p = base[eb[k]] + er[k];
            stage[p].x = pk1[k];
            stage[p].y = pk2[k];
            bkt[p] = (unsigned short)eb[k];
        }
    }
    __syncthreads();

    for (int i = tid; i < count; i += 256) {
        int b = bkt[i];
        binned[gbase[b] + (i - base[b])] = stage[i];
    }
}

// ---------------------------------------------------------------------------
// Pass B: per-bucket local sort by exact dst; emits beg[]/end[].
// Final s_edge record is 4 BYTES: src(17) | positive-bf16-weight(15)<<17.
// ---------------------------------------------------------------------------
__global__ __launch_bounds__(256) void localsort_kernel(
    const int* __restrict__ cursor, const uint2* __restrict__ binned,
    unsigned* __restrict__ s_edge, int* __restrict__ beg, int* __restrict__ end)
{
    __shared__ int deg[NPB];
    __shared__ int rb[NPB];
    __shared__ int cur[NPB];

    const int nb = blockIdx.x;
    const int tid = threadIdx.x;
    const int bstart = nb * BPAD;
    const int count = cursor[nb] - bstart;

    deg[tid] = 0;
    __syncthreads();
    for (int i = tid; i < count; i += 256) {
        unsigned w = binned[bstart + i].x;
        atomicAdd(&deg[(w >> 17) & 255], 1);
    }
    __syncthreads();

    int v = deg[tid];
    rb[tid] = v;
    __syncthreads();
    for (int off = 1; off < 256; off <<= 1) {
        int x = (tid >= off) ? rb[tid - off] : 0;
        __syncthreads();
        rb[tid] += x;
        __syncthreads();
    }
    int ex = rb[tid] - v;
    cur[tid] = ex;
    int node = nb * NPB + tid;
    if (node < N_NODES) {
        beg[node] = bstart + ex;
        end[node] = bstart + ex + v;
    }
    __syncthreads();

    for (int i = tid; i < count; i += 256) {
        uint2 e = binned[bstart + i];
        int d = (e.x >> 17) & 255;
        int r = atomicAdd(&cur[d], 1);
        unsigned wb = (unsigned)f2bf(__uint_as_float(e.y)) & 0x7FFF; // w > 0
        s_edge[bstart + r] = (e.x & 0x1FFFF) | (wb << 17);
    }
}

// ---------------------------------------------------------------------------
// Per-layer aggregation v6: group-per-node eighth-wave, fp8 h rows.
// Wave = 8 nodes; 8-lane group owns one node (fl = lane&7 -> feature octet
// as uint2 = 8 fp8). One VMEM instruction fetches 8 different 64B rows;
// 4 chains/group -> 32 rows in flight per wave. HW fp8->f32 converters
// (v_cvt_pk_f32_fp8) unpack. fp32 accumulate; z written bf16 (MLP input
// precision preserved). Edge runs (4B records) staged in wave-private LDS.
// ---------------------------------------------------------------------------
__global__ __launch_bounds__(256) void gather_kernel(
    const uint2* __restrict__ h8, const int* __restrict__ beg,
    const int* __restrict__ end, const unsigned* __restrict__ s_edge,
    const float* __restrict__ eps, int l, uint4* __restrict__ z4)
{
    __shared__ unsigned eds[4 * WECAP];

    const int w    = threadIdx.x >> 6;
    const int lane = threadIdx.x & 63;
    const int o    = lane >> 3;      // node slot within wave (0..7)
    const int fl   = lane & 7;       // feature octet (features 8*fl..8*fl+7)
    const int nbase = blockIdx.x * GNODES + w * 8;
    const int node  = nbase + o;

    const int ebeg = beg[nbase];
    const int cnt  = end[nbase + 7] - ebeg;
    unsigned* wl = &eds[w * WECAP];
    const bool lds_ok = (cnt <= WECAP);
    if (lds_ok) {
        for (int i = lane; i < cnt; i += 64) wl[i] = s_edge[ebeg + i];
    }

    const int gbeg = beg[node];
    const int deg  = end[node] - gbeg;

    float acc[4][8];
    #pragma unroll
    for (int c = 0; c < 4; ++c)
        #pragma unroll
        for (int j = 0; j < 8; ++j) acc[c][j] = 0.f;

    const uint2* hfl = h8 + fl;

    if (lds_ok) {
        const int bi = gbeg - ebeg;
        for (int it = 0; it < deg; it += 4) {
            #pragma unroll
            for (int c = 0; c < 4; ++c) {
                bool ok = (it + c) < deg;
                int idx = ok ? (bi + it + c) : bi;
                unsigned p = wl[idx];
                float wv = ok ? __uint_as_float((p >> 17) << 16) : 0.f;
                uint2 r = hfl[(long)(p & 0x1FFFF) * 8];
                float2v f01 = __builtin_amdgcn_cvt_pk_f32_fp8(r.x, false);
                float2v f23 = __builtin_amdgcn_cvt_pk_f32_fp8(r.x, true);
                float2v f45 = __builtin_amdgcn_cvt_pk_f32_fp8(r.y, false);
                float2v f67 = __builtin_amdgcn_cvt_pk_f32_fp8(r.y, true);
                acc[c][0] += f01.x * wv;  acc[c][1] += f01.y * wv;
                acc[c][2] += f23.x * wv;  acc[c][3] += f23.y * wv;
                acc[c][4] += f45.x * wv;  acc[c][5] += f45.y * wv;
                acc[c][6] += f67.x * wv;  acc[c][7] += f67.y * wv;
            }
        }
    } else {
        for (int it = 0; it < deg; it += 4) {
            #pragma unroll
            for (int c = 0; c < 4; ++c) {
                bool ok = (it + c) < deg;
                int idx = ok ? (gbeg + it + c) : gbeg;
                unsigned p = s_edge[idx];
                float wv = ok ? __uint_as_float((p >> 17) << 16) : 0.f;
                uint2 r = hfl[(long)(p & 0x1FFFF) * 8];
                float2v f01 = __builtin_amdgcn_cvt_pk_f32_fp8(r.x, false);
                float2v f23 = __builtin_amdgcn_cvt_pk_f32_fp8(r.x, true);
                float2v f45 = __builtin_amdgcn_cvt_pk_f32_fp8(r.y, false);
                float2v f67 = __builtin_amdgcn_cvt_pk_f32_fp8(r.y, true);
                acc[c][0] += f01.x * wv;  acc[c][1] += f01.y * wv;
                acc[c][2] += f23.x * wv;  acc[c][3] += f23.y * wv;
                acc[c][4] += f45.x * wv;  acc[c][5] += f45.y * wv;
                acc[c][6] += f67.x * wv;  acc[c][7] += f67.y * wv;
            }
        }
    }

    float s[8];
    #pragma unroll
    for (int j = 0; j < 8; ++j)
        s[j] = (acc[0][j] + acc[1][j]) + (acc[2][j] + acc[3][j]);

    const float e1 = 1.0f + eps[l];
    uint2 selfr = hfl[(long)node * 8];
    float2v s01 = __builtin_amdgcn_cvt_pk_f32_fp8(selfr.x, false);
    float2v s23 = __builtin_amdgcn_cvt_pk_f32_fp8(selfr.x, true);
    float2v s45 = __builtin_amdgcn_cvt_pk_f32_fp8(selfr.y, false);
    float2v s67 = __builtin_amdgcn_cvt_pk_f32_fp8(selfr.y, true);
    float z0 = e1 * s01.x + s[0];
    float z1 = e1 * s01.y + s[1];
    float z2 = e1 * s23.x + s[2];
    float z3 = e1 * s23.y + s[3];
    float z4v = e1 * s45.x + s[4];
    float z5 = e1 * s45.y + s[5];
    float z6 = e1 * s67.x + s[6];
    float z7 = e1 * s67.y + s[7];
    uint4 ov;
    ov.x = (unsigned)f2bf(z0) | ((unsigned)f2bf(z1) << 16);
    ov.y = (unsigned)f2bf(z2) | ((unsigned)f2bf(z3) << 16);
    ov.z = (unsigned)f2bf(z4v) | ((unsigned)f2bf(z5) << 16);
    ov.w = (unsigned)f2bf(z6) | ((unsigned)f2bf(z7) << 16);
    z4[(long)node * 8 + fl] = ov;
}

// ---------------------------------------------------------------------------
// MFMA MLP + pooling. 80 rows/block, 5 waves (16-row strip each).
// t and h written IN PLACE into the wave-private zs strip (no mid barrier).
// h_out (fp8, for the next gather) skipped on the last layer.
// ---------------------------------------------------------------------------
__global__ __launch_bounds__(MLP_THREADS) void mlp_kernel(
    const unsigned short* __restrict__ z_in,
    const unsigned short* __restrict__ W1t, const unsigned short* __restrict__ W2t,
    const float* __restrict__ b1l, const float* __restrict__ b2l,
    int l, uint2* __restrict__ h_out8, float* __restrict__ pooled)
{
    __shared__ __align__(16) unsigned short zs[MROWS * LPITCH];
    __shared__ __align__(16) unsigned short w1s[DD * LPITCH];
    __shared__ __align__(16) unsigned short w2s[DD * LPITCH];
    __shared__ float red[5 * DD];

    const int tid  = threadIdx.x;
    const int lane = tid & 63;
    const int w    = tid >> 6;
    const int m15  = lane & 15;
    const int quad = lane >> 4;
    const long base = (long)blockIdx.x * MROWS;

    for (int idx = tid; idx < MROWS * 8; idx += MLP_THREADS) {
        int row = idx >> 3, seg = idx & 7;
        *(int4*)&zs[row * LPITCH + seg * 8] =
            *(const int4*)&z_in[(base + row) * DD + seg * 8];
    }
    for (int idx = tid; idx < DD * 8; idx += MLP_THREADS) {
        int row = idx >> 3, seg = idx & 7;
        *(int4*)&w1s[row * LPITCH + seg * 8] =
            *(const int4*)&W1t[(size_t)l * DD * DD + row * DD + seg * 8];
        *(int4*)&w2s[row * LPITCH + seg * 8] =
            *(const int4*)&W2t[(size_t)l * DD * DD + row * DD + seg * 8];
    }
    __syncthreads();

    // GEMM 1: t = leaky(z @ W1 + b1), in place into the wave's strip
    {
        short8 a0 = *(const short8*)&zs[(w * 16 + m15) * LPITCH + quad * 8];
        short8 a1 = *(const short8*)&zs[(w * 16 + m15) * LPITCH + 32 + quad * 8];
        #pragma unroll
        for (int n = 0; n < 4; ++n) {
            short8 b0 = *(const short8*)&w1s[(n * 16 + m15) * LPITCH + quad * 8];
            short8 b1 = *(const short8*)&w1s[(n * 16 + m15) * LPITCH + 32 + quad * 8];
            float4v acc = {0.f, 0.f, 0.f, 0.f};
            acc = __builtin_amdgcn_mfma_f32_16x16x32_bf16(a0, b0, acc, 0, 0, 0);
            acc = __builtin_amdgcn_mfma_f32_16x16x32_bf16(a1, b1, acc, 0, 0, 0);
            int col = n * 16 + m15;
            float bv = b1l[col];
            #pragma unroll
            for (int r = 0; r < 4; ++r) {
                int row = w * 16 + quad * 4 + r;
                float t = acc[r] + bv;
                t = t > 0.0f ? t : 0.01f * t;
                zs[row * LPITCH + col] = f2bf(t);
            }
        }
    }

    // GEMM 2: z2 = t @ W2 + b2; h = leaky(z2) in place; pool z2
    float psum[4];
    {
        short8 a0 = *(const short8*)&zs[(w * 16 + m15) * LPITCH + quad * 8];
        short8 a1 = *(const short8*)&zs[(w * 16 + m15) * LPITCH + 32 + quad * 8];
        #pragma unroll
        for (int n = 0; n < 4; ++n) {
            short8 b0 = *(const short8*)&w2s[(n * 16 + m15) * LPITCH + quad * 8];
            short8 b1 = *(const short8*)&w2s[(n * 16 + m15) * LPITCH + 32 + quad * 8];
            float4v acc = {0.f, 0.f, 0.f, 0.f};
            acc = __builtin_amdgcn_mfma_f32_16x16x32_bf16(a0, b0, acc, 0, 0, 0);
            acc = __builtin_amdgcn_mfma_f32_16x16x32_bf16(a1, b1, acc, 0, 0, 0);
            int col = n * 16 + m15;
            float bv = b2l[col];
            float ps = 0.0f;
            #pragma unroll
            for (int r = 0; r < 4; ++r) {
                int row = w * 16 + quad * 4 + r;
                float z2 = acc[r] + bv;
                ps += z2;
                float hv = z2 > 0.0f ? z2 : 0.01f * z2;
                zs[row * LPITCH + col] = f2bf(hv);
            }
            psum[n] = ps;
        }
    }
    #pragma unroll
    for (int n = 0; n < 4; ++n) {
        float v = psum[n];
        v += __shfl_xor(v, 16);
        v += __shfl_xor(v, 32);
        if (quad == 0) red[w * DD + n * 16 + m15] = v;
    }
    __syncthreads();

    if (h_out8) {
        for (int idx = tid; idx < MROWS * 8; idx += MLP_THREADS) {
            int row = idx >> 3, seg = idx & 7;
            int4 v = *(const int4*)&zs[row * LPITCH + seg * 8];   // 8 bf16
            int lo = 0, hi = 0;
            lo = __builtin_amdgcn_cvt_pk_fp8_f32(bflo((unsigned)v.x), bfhi((unsigned)v.x), lo, 0);
            lo = __builtin_amdgcn_cvt_pk_fp8_f32(bflo((unsigned)v.y), bfhi((unsigned)v.y), lo, 1);
            hi = __builtin_amdgcn_cvt_pk_fp8_f32(bflo((unsigned)v.z), bfhi((unsigned)v.z), hi, 0);
            hi = __builtin_amdgcn_cvt_pk_fp8_f32(bflo((unsigned)v.w), bfhi((unsigned)v.w), hi, 1);
            uint2 o; o.x = (unsigned)lo; o.y = (unsigned)hi;
            h_out8[(base + row) * 8 + seg] = o;
        }
    }
    if (tid < DD) {
        float tot = red[tid] + red[DD + tid] + red[2 * DD + tid]
                  + red[3 * DD + tid] + red[4 * DD + tid];
        int g = blockIdx.x / (NODES_PER_GRAPH / MROWS);
        atomicAdd(&pooled[g * CAT_D + l * DD + tid], tot);
    }
}

// ---------------------------------------------------------------------------
// out[g, j] = pooled[g, :] @ lin_w[:, j] + lin_b[j]
// ---------------------------------------------------------------------------
__global__ __launch_bounds__(64) void final_kernel(
    const float* __restrict__ pooled, const float* __restrict__ lin_w,
    const float* __restrict__ lin_b, float* __restrict__ out)
{
    int g = blockIdx.x;
    int j = threadIdx.x;
    float acc = lin_b[j];
    for (int k = 0; k < CAT_D; ++k)
        acc += pooled[g * CAT_D + k] * lin_w[k * DD + j];
    out[g * DD + j] = acc;
}

extern "C" void kernel_launch(void* const* d_in, const int* in_sizes, int n_in,
                              void* d_out, int out_size, void* d_ws, size_t ws_size,
                              hipStream_t stream)
{
    const float* x     = (const float*)d_in[0];
    const int*   ei    = (const int*)d_in[1];
    const float* ew    = (const float*)d_in[2];
    const float* W1    = (const float*)d_in[4];
    const float* b1    = (const float*)d_in[5];
    const float* W2    = (const float*)d_in[6];
    const float* b2    = (const float*)d_in[7];
    const float* eps   = (const float*)d_in[8];
    const float* lin_w = (const float*)d_in[9];
    const float* lin_b = (const float*)d_in[10];
    float* out = (float*)d_out;

    const int* src = ei;
    const int* dst = ei + N_EDGES;

    char* wsb = (char*)d_ws;
    size_t off = 0;
    auto alloc = [&](size_t bytes) -> void* {
        off = (off + 15) & ~(size_t)15;
        void* p = wsb + off;
        off += bytes;
        return p;
    };
    uint2*  hX    = (uint2*)alloc((size_t)N_NODES * DD);          // fp8, 6.4 MB
    uint2*  hA    = (uint2*)alloc((size_t)N_NODES * DD);          // fp8
    unsigned short* zbuf = (unsigned short*)alloc((size_t)N_NODES * DD * 2); // bf16
    unsigned short* W1t  = (unsigned short*)alloc((size_t)NLAYER * DD * DD * 2);
    unsigned short* W2t  = (unsigned short*)alloc((size_t)NLAYER * DD * DD * 2);
    float* pooled        = (float*)alloc((size_t)NUM_GRAPHS * CAT_D * 4);
    int*   cursor        = (int*)alloc((size_t)NB * 4);
    int*   beg           = (int*)alloc((size_t)N_NODES * 4);
    int*   end_          = (int*)alloc((size_t)N_NODES * 4);
    uint2* binned        = (uint2*)alloc((size_t)NB * BPAD * 8);
    unsigned* s_edge     = (unsigned*)alloc((size_t)NB * BPAD * 4);

    convert_x_kernel<<<(N_NODES * DD / 8 + 255) / 256, 256, 0, stream>>>(x, hX);
    convert_w_kernel<<<(2 * NLAYER * DD * DD + 255) / 256, 256, 0, stream>>>(
        W1, W2, W1t, W2t, cursor);

    bin_kernel<<<(N_EDGES + ECHUNK - 1) / ECHUNK, 256, 0, stream>>>(
        src, dst, ew, cursor, binned);
    localsort_kernel<<<NB, 256, 0, stream>>>(cursor, binned, s_edge, beg, end_);

    hipMemsetAsync(pooled, 0, NUM_GRAPHS * CAT_D * sizeof(float), stream);

    // layers: hX -> hA -> hX -> (none, h dead after last layer)
    const uint2* h_ins[3]  = { hX, hA, hX };
    uint2*       h_outs[3] = { hA, hX, nullptr };
    for (int l = 0; l < NLAYER; ++l) {
        gather_kernel<<<N_NODES / GNODES, 256, 0, stream>>>(
            h_ins[l], beg, end_, s_edge, eps, l, (uint4*)zbuf);

        mlp_kernel<<<N_NODES / MROWS, MLP_THREADS, 0, stream>>>(
            zbuf, W1t, W2t,
            b1 + (size_t)l * DD, b2 + (size_t)l * DD,
            l, h_outs[l], pooled);
    }

    final_kernel<<<NUM_GRAPHS, 64, 0, stream>>>(pooled, lin_w, lin_b, out);
}